// Round 1
// baseline (110.336 us; speedup 1.0000x reference)
//
#include <hip/hip_runtime.h>

#define IGNORE_LABEL 255
#define MIN_KEPT 100000u
#define THRESH 0.7f

constexpr int N_PIX = 2 * 16 * 256 * 256;      // 2097152 pixels (b,d,h,w)
constexpr int C = 16;                          // channels
constexpr int CH_STRIDE = 16 * 256 * 256;      // d*h*w = 1048576
constexpr int B_STRIDE = C * CH_STRIDE;        // 16777216
constexpr int NPART = 2048;                    // reduction partials

struct SelState {
    unsigned prefix;   // selected high bits so far
    unsigned krem;     // remaining rank within selected bin
    float    thresh;   // final threshold = max(0.7, kth smallest)
};

// Pass 1: per-pixel softmax -> mask_prob (target-class prob, invalid->1.0) and nll
__global__ __launch_bounds__(256) void k_compute(const float* __restrict__ pred,
                                                 const int* __restrict__ target,
                                                 float* __restrict__ mask_prob,
                                                 float* __restrict__ nll_out) {
    int n = blockIdx.x * blockDim.x + threadIdx.x;
    if (n >= N_PIX) return;
    int b = n >> 20;
    int rem = n & ((1 << 20) - 1);
    const float* base = pred + b * B_STRIDE + rem;

    float x[C];
#pragma unroll
    for (int c = 0; c < C; ++c) x[c] = base[c * CH_STRIDE];

    int tg = target[n];
    bool valid = (tg != IGNORE_LABEL);
    int t0 = valid ? tg : 0;

    float m = x[0];
#pragma unroll
    for (int c = 1; c < C; ++c) m = fmaxf(m, x[c]);

    float se = 0.0f;
    float xt = x[0];
#pragma unroll
    for (int c = 0; c < C; ++c) {
        se += expf(x[c] - m);
        if (c == t0) xt = x[c];          // compile-time index, predicated select
    }
    float lse = logf(se);
    float d = xt - m;
    nll_out[n] = -(d - lse);
    float p = expf(d) / se;
    mask_prob[n] = valid ? p : 1.0f;
}

// Histogram of float bit patterns (monotonic for values >= 0).
// level 0: all elems, bin = bits >> 20          (4096 bins)
// level 1: elems with bits>>20 == prefix, bin = (bits>>8)&0xFFF (4096 bins)
// level 2: elems with bits>>8  == prefix, bin = bits & 0xFF     (256 bins)
__global__ __launch_bounds__(256) void k_hist(const float* __restrict__ mask_prob,
                                              unsigned* __restrict__ hist,
                                              const SelState* __restrict__ sel,
                                              int level) {
    __shared__ unsigned lh[4096];
    int nb = (level < 2) ? 4096 : 256;
    for (int i = threadIdx.x; i < nb; i += blockDim.x) lh[i] = 0;
    __syncthreads();
    unsigned prefix = (level > 0) ? sel->prefix : 0u;
    int stride = gridDim.x * blockDim.x;
    for (int n = blockIdx.x * blockDim.x + threadIdx.x; n < N_PIX; n += stride) {
        unsigned bits = __float_as_uint(mask_prob[n]);
        if (level == 0) {
            atomicAdd(&lh[bits >> 20], 1u);
        } else if (level == 1) {
            if ((bits >> 20) == prefix) atomicAdd(&lh[(bits >> 8) & 0xFFFu], 1u);
        } else {
            if ((bits >> 8) == prefix) atomicAdd(&lh[bits & 0xFFu], 1u);
        }
    }
    __syncthreads();
    for (int i = threadIdx.x; i < nb; i += blockDim.x) {
        unsigned v = lh[i];
        if (v) atomicAdd(&hist[i], v);
    }
}

// Single-block scan: find the bin containing rank krem, update SelState.
__global__ __launch_bounds__(256) void k_scan(const unsigned* __restrict__ hist,
                                              SelState* __restrict__ sel,
                                              int level) {
    __shared__ unsigned ssum[256];
    int nb = (level < 2) ? 4096 : 256;
    int per = nb / 256;
    unsigned krem = (level == 0) ? MIN_KEPT : sel->krem;
    unsigned prefix = (level == 0) ? 0u : sel->prefix;
    int t = threadIdx.x;

    unsigned local = 0;
    for (int i = 0; i < per; ++i) local += hist[t * per + i];
    ssum[t] = local;
    __syncthreads();
    // Hillis-Steele inclusive scan over 256 per-thread sums
    for (int off = 1; off < 256; off <<= 1) {
        unsigned add = (t >= off) ? ssum[t - off] : 0u;
        __syncthreads();
        ssum[t] += add;
        __syncthreads();
    }
    unsigned exc = ssum[t] - local;   // exclusive prefix for this thread's segment
    if (krem > exc && krem <= exc + local) {   // exactly one thread matches
        unsigned run = exc;
        for (int i = 0; i < per; ++i) {
            unsigned cv = hist[t * per + i];
            if (krem <= run + cv) {
                unsigned bin = (unsigned)(t * per + i);
                if (level == 0) {
                    sel->prefix = bin;
                    sel->krem = krem - run;
                } else if (level == 1) {
                    sel->prefix = (prefix << 12) | bin;
                    sel->krem = krem - run;
                } else {
                    unsigned kbits = (prefix << 8) | bin;
                    float kth = __uint_as_float(kbits);
                    sel->thresh = fmaxf(THRESH, kth);
                }
                break;
            }
            run += cv;
        }
    }
}

// Masked sum of nll and count over kept pixels -> per-block partials (deterministic)
__global__ __launch_bounds__(256) void k_reduce(const float* __restrict__ mask_prob,
                                                const float* __restrict__ nll,
                                                const int* __restrict__ target,
                                                const SelState* __restrict__ sel,
                                                float* __restrict__ psum,
                                                float* __restrict__ pcnt) {
    float thr = sel->thresh;
    int stride = gridDim.x * blockDim.x;
    float s = 0.0f, cnt = 0.0f;
    for (int n = blockIdx.x * blockDim.x + threadIdx.x; n < N_PIX; n += stride) {
        float mp = mask_prob[n];
        int tg = target[n];
        if (tg != IGNORE_LABEL && mp <= thr) {
            s += nll[n];
            cnt += 1.0f;
        }
    }
    // wave reduce
#pragma unroll
    for (int off = 32; off > 0; off >>= 1) {
        s += __shfl_down(s, off);
        cnt += __shfl_down(cnt, off);
    }
    __shared__ float ls[4], lc[4];
    int lane = threadIdx.x & 63, w = threadIdx.x >> 6;
    if (lane == 0) { ls[w] = s; lc[w] = cnt; }
    __syncthreads();
    if (threadIdx.x == 0) {
        float S = 0.0f, Cn = 0.0f;
        for (int i = 0; i < 4; ++i) { S += ls[i]; Cn += lc[i]; }
        psum[blockIdx.x] = S;
        pcnt[blockIdx.x] = Cn;
    }
}

__global__ __launch_bounds__(256) void k_final(const float* __restrict__ psum,
                                               const float* __restrict__ pcnt,
                                               float* __restrict__ out) {
    __shared__ double ds[256], dc[256];
    int t = threadIdx.x;
    double s = 0.0, c = 0.0;
    for (int i = t; i < NPART; i += 256) { s += (double)psum[i]; c += (double)pcnt[i]; }
    ds[t] = s; dc[t] = c;
    __syncthreads();
    for (int off = 128; off > 0; off >>= 1) {
        if (t < off) { ds[t] += ds[t + off]; dc[t] += dc[t + off]; }
        __syncthreads();
    }
    if (t == 0) {
        double cnt = dc[0];
        if (cnt < 1.0) cnt = 1.0;
        out[0] = (float)(ds[0] / cnt);
    }
}

extern "C" void kernel_launch(void* const* d_in, const int* in_sizes, int n_in,
                              void* d_out, int out_size, void* d_ws, size_t ws_size,
                              hipStream_t stream) {
    const float* pred = (const float*)d_in[0];
    const int* target = (const int*)d_in[1];
    float* out = (float*)d_out;

    // ws layout
    float* mask_prob = (float*)d_ws;                       // N_PIX f32
    float* nll = mask_prob + N_PIX;                        // N_PIX f32
    unsigned* hist1 = (unsigned*)(nll + N_PIX);            // 4096
    unsigned* hist2 = hist1 + 4096;                        // 4096
    unsigned* hist3 = hist2 + 4096;                        // 256
    SelState* sel = (SelState*)(hist3 + 256);
    float* psum = (float*)(sel + 1);                       // NPART
    float* pcnt = psum + NPART;                            // NPART

    // zero histograms each call (harness does not re-poison between replays)
    hipMemsetAsync(hist1, 0, (4096 + 4096 + 256) * sizeof(unsigned), stream);

    k_compute<<<N_PIX / 256, 256, 0, stream>>>(pred, target, mask_prob, nll);
    k_hist<<<2048, 256, 0, stream>>>(mask_prob, hist1, sel, 0);
    k_scan<<<1, 256, 0, stream>>>(hist1, sel, 0);
    k_hist<<<2048, 256, 0, stream>>>(mask_prob, hist2, sel, 1);
    k_scan<<<1, 256, 0, stream>>>(hist2, sel, 1);
    k_hist<<<2048, 256, 0, stream>>>(mask_prob, hist3, sel, 2);
    k_scan<<<1, 256, 0, stream>>>(hist3, sel, 2);
    k_reduce<<<NPART, 256, 0, stream>>>(mask_prob, nll, target, sel, psum, pcnt);
    k_final<<<1, 256, 0, stream>>>(psum, pcnt, out);
}

// Round 2
// 96.589 us; speedup vs baseline: 1.1423x; 1.1423x over previous
//
#include <hip/hip_runtime.h>

#define IGNORE_LABEL 255
#define MIN_KEPT 100000u
#define THRESH 0.7f

constexpr int N_PIX = 2 * 16 * 256 * 256;      // 2097152 pixels (b,d,h,w)
constexpr int C = 16;                          // channels
constexpr int CH_STRIDE = 16 * 256 * 256;      // d*h*w = 1048576
constexpr int B_STRIDE = C * CH_STRIDE;        // 16777216
constexpr int NBLK = 2048;                     // 2048 blocks * 256 thr * 4 pix = N_PIX

// ---------------------------------------------------------------------------
// Pass A: per-pixel softmax -> mask_prob (target-class prob; invalid -> 1.0),
// plus global count of (mask_prob <= 0.7). 4 pixels/thread, float4 loads.
// ---------------------------------------------------------------------------
__global__ __launch_bounds__(256) void k_compute(const float* __restrict__ pred,
                                                 const int* __restrict__ target,
                                                 float* __restrict__ mask_prob,
                                                 unsigned* __restrict__ cnt_le) {
    int tid = blockIdx.x * 256 + threadIdx.x;
    int n = tid * 4;                       // first of 4 consecutive pixels
    int b = n >> 20;                       // batch (d*h*w = 2^20)
    int rem = n & ((1 << 20) - 1);
    const float* base = pred + b * B_STRIDE + rem;

    float x[C][4];
#pragma unroll
    for (int c = 0; c < C; ++c) {
        float4 v = *reinterpret_cast<const float4*>(base + c * CH_STRIDE);
        x[c][0] = v.x; x[c][1] = v.y; x[c][2] = v.z; x[c][3] = v.w;
    }
    int4 tg4 = *reinterpret_cast<const int4*>(target + n);
    int tgv[4] = {tg4.x, tg4.y, tg4.z, tg4.w};

    float mp[4];
    int cnt = 0;
#pragma unroll
    for (int j = 0; j < 4; ++j) {
        int t = tgv[j];
        bool valid = (t != IGNORE_LABEL);
        int t0 = valid ? t : 0;
        float m = x[0][j];
#pragma unroll
        for (int c = 1; c < C; ++c) m = fmaxf(m, x[c][j]);
        float se = 0.0f;
        float xt = x[0][j];
#pragma unroll
        for (int c = 0; c < C; ++c) {
            se += __expf(x[c][j] - m);
            if (c == t0) xt = x[c][j];     // compile-time c vs runtime t0 -> cndmask
        }
        float p = __expf(xt - m) / se;
        mp[j] = valid ? p : 1.0f;
        cnt += (mp[j] <= THRESH) ? 1 : 0;
    }
    float4 o; o.x = mp[0]; o.y = mp[1]; o.z = mp[2]; o.w = mp[3];
    *reinterpret_cast<float4*>(mask_prob + n) = o;

    // block-reduce cnt, one atomic per block
#pragma unroll
    for (int off = 32; off > 0; off >>= 1) cnt += __shfl_down(cnt, off);
    __shared__ int lc[4];
    int lane = threadIdx.x & 63, w = threadIdx.x >> 6;
    if (lane == 0) lc[w] = cnt;
    __syncthreads();
    if (threadIdx.x == 0) {
        unsigned tot = (unsigned)(lc[0] + lc[1] + lc[2] + lc[3]);
        if (tot) atomicAdd(cnt_le, tot);
    }
}

// ---------------------------------------------------------------------------
// Pass B: threshold selection. Fast path: if count(p<=0.7) >= MIN_KEPT the
// kth smallest is <= 0.7, so threshold = 0.7 exactly. Otherwise (never for
// this input) run an exact 3-level radix select in a single block using LDS
// histograms over the float bit pattern (monotonic for values in [0,1]).
// ---------------------------------------------------------------------------
__global__ __launch_bounds__(256) void k_select(const float* __restrict__ mask_prob,
                                                const unsigned* __restrict__ cnt_le,
                                                float* __restrict__ thresh_out) {
    if (*cnt_le >= MIN_KEPT) {
        if (threadIdx.x == 0) *thresh_out = THRESH;
        return;
    }
    // slow exact path (kth > 0.7)
    __shared__ unsigned h[4096];
    __shared__ unsigned s_bin, s_krem;
    int tid = threadIdx.x;

    // level 0: bits >> 20 (4096 bins)
    for (int i = tid; i < 4096; i += 256) h[i] = 0;
    __syncthreads();
    for (int nn = tid; nn < N_PIX; nn += 256)
        atomicAdd(&h[__float_as_uint(mask_prob[nn]) >> 20], 1u);
    __syncthreads();
    if (tid == 0) {
        unsigned run = 0;
        for (unsigned bb = 0; bb < 4096; ++bb) {
            unsigned cv = h[bb];
            if (MIN_KEPT <= run + cv) { s_bin = bb; s_krem = MIN_KEPT - run; break; }
            run += cv;
        }
    }
    __syncthreads();
    unsigned p0 = s_bin, k1 = s_krem;

    // level 1: (bits >> 8) & 0xFFF (4096 bins), prefix = p0
    __syncthreads();
    for (int i = tid; i < 4096; i += 256) h[i] = 0;
    __syncthreads();
    for (int nn = tid; nn < N_PIX; nn += 256) {
        unsigned bits = __float_as_uint(mask_prob[nn]);
        if ((bits >> 20) == p0) atomicAdd(&h[(bits >> 8) & 0xFFFu], 1u);
    }
    __syncthreads();
    if (tid == 0) {
        unsigned run = 0;
        for (unsigned bb = 0; bb < 4096; ++bb) {
            unsigned cv = h[bb];
            if (k1 <= run + cv) { s_bin = bb; s_krem = k1 - run; break; }
            run += cv;
        }
    }
    __syncthreads();
    unsigned p1 = (p0 << 12) | s_bin;
    unsigned k2 = s_krem;

    // level 2: bits & 0xFF (256 bins), prefix = p1
    __syncthreads();
    for (int i = tid; i < 256; i += 256) h[i] = 0;
    __syncthreads();
    for (int nn = tid; nn < N_PIX; nn += 256) {
        unsigned bits = __float_as_uint(mask_prob[nn]);
        if ((bits >> 8) == p1) atomicAdd(&h[bits & 0xFFu], 1u);
    }
    __syncthreads();
    if (tid == 0) {
        unsigned run = 0;
        for (unsigned bb = 0; bb < 256; ++bb) {
            unsigned cv = h[bb];
            if (k2 <= run + cv) {
                *thresh_out = fmaxf(THRESH, __uint_as_float((p1 << 8) | bb));
                break;
            }
            run += cv;
        }
    }
}

// ---------------------------------------------------------------------------
// Pass C: masked mean of nll = -log(mask_prob) over kept pixels.
// Deterministic: fixed per-block partials, last block finishes in double.
// ---------------------------------------------------------------------------
__global__ __launch_bounds__(256) void k_reduce(const float* __restrict__ mask_prob,
                                                const int* __restrict__ target,
                                                const float* __restrict__ thresh,
                                                float* __restrict__ psum,
                                                float* __restrict__ pcnt,
                                                unsigned* __restrict__ done_ctr,
                                                float* __restrict__ out) {
    float thr = *thresh;
    int tid = blockIdx.x * 256 + threadIdx.x;
    int n = tid * 4;
    float4 mp4 = *reinterpret_cast<const float4*>(mask_prob + n);
    int4 tg4 = *reinterpret_cast<const int4*>(target + n);
    float mpv[4] = {mp4.x, mp4.y, mp4.z, mp4.w};
    int tgv[4] = {tg4.x, tg4.y, tg4.z, tg4.w};

    float s = 0.0f, c = 0.0f;
#pragma unroll
    for (int j = 0; j < 4; ++j) {
        float l = -__logf(mpv[j]);                 // finite for mp in (0,1]
        float keep = (tgv[j] != IGNORE_LABEL && mpv[j] <= thr) ? 1.0f : 0.0f;
        s += keep * l;
        c += keep;
    }
#pragma unroll
    for (int off = 32; off > 0; off >>= 1) {
        s += __shfl_down(s, off);
        c += __shfl_down(c, off);
    }
    __shared__ float ls[4], lcnt[4];
    int lane = threadIdx.x & 63, w = threadIdx.x >> 6;
    if (lane == 0) { ls[w] = s; lcnt[w] = c; }
    __syncthreads();

    __shared__ bool amLast;
    if (threadIdx.x == 0) {
        psum[blockIdx.x] = ls[0] + ls[1] + ls[2] + ls[3];
        pcnt[blockIdx.x] = lcnt[0] + lcnt[1] + lcnt[2] + lcnt[3];
        __threadfence();                            // release partials (device scope)
        unsigned old = atomicAdd(done_ctr, 1u);
        amLast = (old == (unsigned)(gridDim.x - 1));
    }
    __syncthreads();
    if (!amLast) return;

    __threadfence();                                // acquire other blocks' partials
    double ds = 0.0, dc = 0.0;
    for (int i = threadIdx.x; i < NBLK; i += 256) {
        ds += (double)psum[i];
        dc += (double)pcnt[i];
    }
    __shared__ double rs[256], rc[256];
    rs[threadIdx.x] = ds; rc[threadIdx.x] = dc;
    __syncthreads();
    for (int off = 128; off > 0; off >>= 1) {
        if (threadIdx.x < off) {
            rs[threadIdx.x] += rs[threadIdx.x + off];
            rc[threadIdx.x] += rc[threadIdx.x + off];
        }
        __syncthreads();
    }
    if (threadIdx.x == 0) {
        double cn = rc[0] < 1.0 ? 1.0 : rc[0];
        out[0] = (float)(rs[0] / cn);
    }
}

extern "C" void kernel_launch(void* const* d_in, const int* in_sizes, int n_in,
                              void* d_out, int out_size, void* d_ws, size_t ws_size,
                              hipStream_t stream) {
    const float* pred = (const float*)d_in[0];
    const int* target = (const int*)d_in[1];
    float* out = (float*)d_out;

    // ws layout (ws poisoned 0xAA once; we re-init what we read-before-write)
    unsigned* cnt_le = (unsigned*)d_ws;            // [0]
    unsigned* done_ctr = cnt_le + 1;               // [1]
    float* thresh = (float*)(cnt_le + 2);          // [2] written by k_select
    float* mask_prob = (float*)d_ws + 64;          // 256 B offset, N_PIX floats
    float* psum = mask_prob + N_PIX;               // NBLK floats
    float* pcnt = psum + NBLK;                     // NBLK floats

    hipMemsetAsync(d_ws, 0, 8, stream);            // cnt_le, done_ctr

    k_compute<<<NBLK, 256, 0, stream>>>(pred, target, mask_prob, cnt_le);
    k_select<<<1, 256, 0, stream>>>(mask_prob, cnt_le, thresh);
    k_reduce<<<NBLK, 256, 0, stream>>>(mask_prob, target, thresh,
                                       psum, pcnt, done_ctr, out);
}

// Round 3
// 36.069 us; speedup vs baseline: 3.0590x; 2.6779x over previous
//
#include <hip/hip_runtime.h>

#define IGNORE_LABEL 255
#define MIN_KEPT 100000u
#define THRESH 0.7f

constexpr int N_PIX = 1 << 21;                 // 2*16*256*256 pixels (b,d,h,w)
constexpr int C = 16;                          // channels
constexpr int CH_STRIDE = 1 << 20;             // d*h*w
constexpr int B_STRIDE = C * CH_STRIDE;
constexpr int NBLK = 2048;                     // 2048 blk * 256 thr * 4 pix = N_PIX

// ---------------------------------------------------------------------------
// Fused pass: per-pixel softmax; speculative OHEM sums assuming threshold=0.7.
// kept = valid && p_target <= 0.7  (invalid pixels have mp=1.0 > 0.7, so this
// count is simultaneously count(mask_prob <= 0.7) for the MIN_KEPT check).
// Per-block partials written unconditionally -> no atomics, no init, no memset.
// ---------------------------------------------------------------------------
__global__ __launch_bounds__(256) void k_fused(const float* __restrict__ pred,
                                               const int* __restrict__ target,
                                               float* __restrict__ psum,
                                               float* __restrict__ pcnt) {
    int tid = blockIdx.x * 256 + threadIdx.x;
    int n = tid * 4;                           // 4 consecutive pixels
    int b = n >> 20;
    int rem = n & (CH_STRIDE - 1);
    const float* base = pred + b * B_STRIDE + rem;

    float x[C][4];
#pragma unroll
    for (int c = 0; c < C; ++c) {
        float4 v = *reinterpret_cast<const float4*>(base + c * CH_STRIDE);
        x[c][0] = v.x; x[c][1] = v.y; x[c][2] = v.z; x[c][3] = v.w;
    }
    int4 tg4 = *reinterpret_cast<const int4*>(target + n);
    int tgv[4] = {tg4.x, tg4.y, tg4.z, tg4.w};

    float s = 0.0f, cn = 0.0f;
#pragma unroll
    for (int j = 0; j < 4; ++j) {
        int t = tgv[j];
        bool valid = (t != IGNORE_LABEL);
        int t0 = valid ? t : 0;
        float m = x[0][j];
#pragma unroll
        for (int c = 1; c < C; ++c) m = fmaxf(m, x[c][j]);
        float se = 0.0f;
        float xt = x[0][j];
#pragma unroll
        for (int c = 0; c < C; ++c) {
            se += __expf(x[c][j] - m);
            if (c == t0) xt = x[c][j];         // compile-time c vs runtime t0 -> cndmask
        }
        float d = xt - m;
        float p = __expf(d) / se;
        float mp = valid ? p : 1.0f;
        float keep = (mp <= THRESH) ? 1.0f : 0.0f;
        float nll = __logf(se) - d;            // -log softmax[target], direct form
        s += keep * nll;
        cn += keep;
    }

    // wave + block reduce (deterministic order)
#pragma unroll
    for (int off = 32; off > 0; off >>= 1) {
        s += __shfl_down(s, off);
        cn += __shfl_down(cn, off);
    }
    __shared__ float ls[4], lc[4];
    int lane = threadIdx.x & 63, w = threadIdx.x >> 6;
    if (lane == 0) { ls[w] = s; lc[w] = cn; }
    __syncthreads();
    if (threadIdx.x == 0) {
        psum[blockIdx.x] = ls[0] + ls[1] + ls[2] + ls[3];
        pcnt[blockIdx.x] = lc[0] + lc[1] + lc[2] + lc[3];
    }
}

// Scalar recompute of masked target-prob + nll for one pixel (slow path only).
__device__ __noinline__ float slow_prob(const float* __restrict__ pred,
                                        const int* __restrict__ target,
                                        int n, float* nll) {
    int b = n >> 20, rem = n & (CH_STRIDE - 1);
    const float* base = pred + b * B_STRIDE + rem;
    int t = target[n];
    bool valid = (t != IGNORE_LABEL);
    int t0 = valid ? t : 0;
    float xs[C], m = -1e30f;
#pragma unroll
    for (int c = 0; c < C; ++c) { xs[c] = base[c * CH_STRIDE]; m = fmaxf(m, xs[c]); }
    float se = 0.0f, xt = xs[0];
#pragma unroll
    for (int c = 0; c < C; ++c) {
        se += __expf(xs[c] - m);
        if (c == t0) xt = xs[c];
    }
    float d = xt - m;
    *nll = __logf(se) - d;
    float p = __expf(d) / se;
    return valid ? p : 1.0f;
}

// ---------------------------------------------------------------------------
// Final: combine partials. Fast path (cnt >= MIN_KEPT): threshold is exactly
// 0.7, speculative sums are the answer. Slow path (never taken for this
// input, kept for correctness): exact 3-level radix select over recomputed
// mask_prob bit patterns, then masked mean.
// ---------------------------------------------------------------------------
__global__ __launch_bounds__(256) void k_final(const float* __restrict__ psum,
                                               const float* __restrict__ pcnt,
                                               const float* __restrict__ pred,
                                               const int* __restrict__ target,
                                               float* __restrict__ out) {
    int tid = threadIdx.x;
    __shared__ double rs[256], rc[256];
    double s = 0.0, c = 0.0;
    for (int i = tid; i < NBLK; i += 256) { s += (double)psum[i]; c += (double)pcnt[i]; }
    rs[tid] = s; rc[tid] = c;
    __syncthreads();
    for (int off = 128; off > 0; off >>= 1) {
        if (tid < off) { rs[tid] += rs[tid + off]; rc[tid] += rc[tid + off]; }
        __syncthreads();
    }
    double tots = rs[0], totc = rc[0];        // uniform across block after sync

    if (totc >= (double)MIN_KEPT) {
        if (tid == 0) out[0] = (float)(tots / (totc < 1.0 ? 1.0 : totc));
        return;                                // uniform exit
    }

    // ---- slow exact path ----
    __shared__ unsigned h[4096];
    __shared__ unsigned s_bin, s_krem;
    float dummy;

    // level 0: bits >> 20
    for (int i = tid; i < 4096; i += 256) h[i] = 0;
    __syncthreads();
    for (int nn = tid; nn < N_PIX; nn += 256) {
        unsigned bits = __float_as_uint(slow_prob(pred, target, nn, &dummy));
        atomicAdd(&h[bits >> 20], 1u);
    }
    __syncthreads();
    if (tid == 0) {
        unsigned run = 0;
        for (unsigned bb = 0; bb < 4096; ++bb) {
            unsigned cv = h[bb];
            if (MIN_KEPT <= run + cv) { s_bin = bb; s_krem = MIN_KEPT - run; break; }
            run += cv;
        }
    }
    __syncthreads();
    unsigned p0 = s_bin, k1 = s_krem;
    __syncthreads();

    // level 1: (bits >> 8) & 0xFFF
    for (int i = tid; i < 4096; i += 256) h[i] = 0;
    __syncthreads();
    for (int nn = tid; nn < N_PIX; nn += 256) {
        unsigned bits = __float_as_uint(slow_prob(pred, target, nn, &dummy));
        if ((bits >> 20) == p0) atomicAdd(&h[(bits >> 8) & 0xFFFu], 1u);
    }
    __syncthreads();
    if (tid == 0) {
        unsigned run = 0;
        for (unsigned bb = 0; bb < 4096; ++bb) {
            unsigned cv = h[bb];
            if (k1 <= run + cv) { s_bin = bb; s_krem = k1 - run; break; }
            run += cv;
        }
    }
    __syncthreads();
    unsigned p1 = (p0 << 12) | s_bin;
    unsigned k2 = s_krem;
    __syncthreads();

    // level 2: bits & 0xFF
    for (int i = tid; i < 256; i += 256) h[i] = 0;
    __syncthreads();
    for (int nn = tid; nn < N_PIX; nn += 256) {
        unsigned bits = __float_as_uint(slow_prob(pred, target, nn, &dummy));
        if ((bits >> 8) == p1) atomicAdd(&h[bits & 0xFFu], 1u);
    }
    __syncthreads();
    if (tid == 0) {
        unsigned run = 0;
        for (unsigned bb = 0; bb < 256; ++bb) {
            unsigned cv = h[bb];
            if (k2 <= run + cv) { s_bin = (p1 << 8) | bb; break; }
            run += cv;
        }
    }
    __syncthreads();
    float thr = fmaxf(THRESH, __uint_as_float(s_bin));

    // masked mean at exact threshold
    double fs = 0.0, fc = 0.0;
    for (int nn = tid; nn < N_PIX; nn += 256) {
        float nll;
        float mp = slow_prob(pred, target, nn, &nll);
        if (target[nn] != IGNORE_LABEL && mp <= thr) { fs += (double)nll; fc += 1.0; }
    }
    __syncthreads();
    rs[tid] = fs; rc[tid] = fc;
    __syncthreads();
    for (int off = 128; off > 0; off >>= 1) {
        if (tid < off) { rs[tid] += rs[tid + off]; rc[tid] += rc[tid + off]; }
        __syncthreads();
    }
    if (tid == 0) {
        double cc = rc[0] < 1.0 ? 1.0 : rc[0];
        out[0] = (float)(rs[0] / cc);
    }
}

extern "C" void kernel_launch(void* const* d_in, const int* in_sizes, int n_in,
                              void* d_out, int out_size, void* d_ws, size_t ws_size,
                              hipStream_t stream) {
    const float* pred = (const float*)d_in[0];
    const int* target = (const int*)d_in[1];
    float* out = (float*)d_out;

    float* psum = (float*)d_ws;                // NBLK floats, written before read
    float* pcnt = psum + NBLK;                 // NBLK floats

    k_fused<<<NBLK, 256, 0, stream>>>(pred, target, psum, pcnt);
    k_final<<<1, 256, 0, stream>>>(psum, pcnt, pred, target, out);
}